// Round 5
// baseline (97.836 us; speedup 1.0000x reference)
//
#include <hip/hip_runtime.h>

#define NNODES   50000
#define DEG      16
#define NEDGES   (NNODES * DEG)
#define INF      128
#define OUTF     128
#define KDIM     256      // 2*IN_FEATS
#define NTHREADS 256

#define NBM      32       // nodes per main-kernel block
#define HSS      264      // hs row stride in bf16 (256 + 8 pad)
#define NBLK     ((NNODES + NBM - 1) / NBM)        // 1563
#define CONV_BLOCKS (NNODES * INF / 8 / 256)       // 3125
#define PACK_BLOCKS (KDIM * OUTF / 8 / 256)        // 16

// ---------------- helpers ----------------
static __device__ __forceinline__ unsigned int bfpack(float x, float y) {
    unsigned int ux = __float_as_uint(x), uy = __float_as_uint(y);
    ux = (ux + 0x7fffu + ((ux >> 16) & 1u)) >> 16;
    uy = (uy + 0x7fffu + ((uy >> 16) & 1u)) >> 16;
    return ux | (uy << 16);
}
static __device__ __forceinline__ float bflo(unsigned int u) { return __uint_as_float(u << 16); }
static __device__ __forceinline__ float bfhi(unsigned int u) { return __uint_as_float(u & 0xffff0000u); }

typedef __attribute__((ext_vector_type(8))) short short8;
typedef __attribute__((ext_vector_type(4))) float f32x4;
typedef __attribute__((ext_vector_type(2))) float f32x2;

// pack 4 f32 -> 4 fp8 e4m3 (one uint)
static __device__ __forceinline__ unsigned int fp8pack4(float a, float b, float c, float d) {
    int w = __builtin_amdgcn_cvt_pk_fp8_f32(a, b, 0, false);
    w = __builtin_amdgcn_cvt_pk_fp8_f32(c, d, w, true);
    return (unsigned int)w;
}

// ---------------- prep: feat f32->fp8  +  W -> B-fragment bf16 pack ----------------
// wB[t][u][lane][j] = W[u*16 + (lane&15)][t*32 + (lane>>4)*8 + j]
__global__ __launch_bounds__(256)
void prep(const float* __restrict__ feat, const float* __restrict__ weight,
          unsigned char* __restrict__ feat8, unsigned short* __restrict__ wB) {
    const int bid = blockIdx.x;
    const int tid = threadIdx.x;
    if (bid < CONV_BLOCKS) {
        const int gid = bid * 256 + tid;               // 8 floats each
        const float4* src = reinterpret_cast<const float4*>(feat + (size_t)gid * 8);
        const float4 f0 = src[0];
        const float4 f1 = src[1];
        uint2 o;
        o.x = fp8pack4(f0.x, f0.y, f0.z, f0.w);
        o.y = fp8pack4(f1.x, f1.y, f1.z, f1.w);
        *reinterpret_cast<uint2*>(feat8 + (size_t)gid * 8) = o;
    } else {
        const int gid = (bid - CONV_BLOCKS) * 256 + tid;   // 4096 groups of 8
        const int lane = gid & 63;
        const int u    = (gid >> 6) & 7;
        const int t    = gid >> 9;
        const int row  = u * 16 + (lane & 15);
        const int kb   = t * 32 + (lane >> 4) * 8;
        const float* src = weight + (size_t)row * KDIM + kb;
        const float4 f0 = *reinterpret_cast<const float4*>(src);
        const float4 f1 = *reinterpret_cast<const float4*>(src + 4);
        uint4 o;
        o.x = bfpack(f0.x, f0.y);
        o.y = bfpack(f0.z, f0.w);
        o.z = bfpack(f1.x, f1.y);
        o.w = bfpack(f1.z, f1.w);
        *reinterpret_cast<uint4*>(wB + (size_t)gid * 8) = o;
    }
}

// ---------------- main: fp8 gather + bf16 MFMA GEMM, 32 nodes/block ----------------
__global__ __launch_bounds__(NTHREADS, 6)
void sage_fp8(const float* __restrict__ feat,
              const int*   __restrict__ off32,
              const void*  __restrict__ indices_raw,
              const unsigned char* __restrict__ feat8,
              const unsigned short* __restrict__ wB,
              const float* __restrict__ bias,
              float*       __restrict__ out)
{
    __shared__ unsigned short hs[NBM][HSS];   // [32][264] bf16 = 16.9 KB
    __shared__ int sidx[NBM * DEG];           // 512 ints = 2 KB

    const int tid  = threadIdx.x;
    const int base = blockIdx.x * NBM;
    const size_t ebase = (size_t)base * DEG;

    const bool idx64 = (off32[1] == 0 && off32[2] == DEG);

    // ---- stage 512 indices into LDS (OOB slots -> 0, safe dummy) ----
    if (idx64) {
        const size_t e = ebase + 2 * (size_t)tid;
        int v0 = 0, v1 = 0;
        if (e + 1 < NEDGES) {
            const longlong2 p = *reinterpret_cast<const longlong2*>(
                reinterpret_cast<const long long*>(indices_raw) + e);
            v0 = (int)p.x; v1 = (int)p.y;
        }
        sidx[2 * tid]     = v0;
        sidx[2 * tid + 1] = v1;
    } else if (tid < 128) {
        const size_t e = ebase + 4 * (size_t)tid;
        int4 v = make_int4(0, 0, 0, 0);
        if (e + 3 < NEDGES)
            v = *reinterpret_cast<const int4*>(
                reinterpret_cast<const int*>(indices_raw) + e);
        sidx[4 * tid] = v.x; sidx[4 * tid + 1] = v.y;
        sidx[4 * tid + 2] = v.z; sidx[4 * tid + 3] = v.w;
    }

    const int g    = tid >> 3;    // local node 0..31
    const int c8   = tid & 7;     // 16-column slice 0..7
    const int node = base + g;

    // ---- self features: 16 fp32 -> 16 bf16 -> hs[g][c8*16 ..] ----
    {
        uint4 o0 = make_uint4(0, 0, 0, 0), o1 = o0;
        if (node < NNODES) {
            const float4* sp = reinterpret_cast<const float4*>(
                feat + (size_t)node * INF + c8 * 16);
            const float4 f0 = sp[0], f1 = sp[1], f2 = sp[2], f3 = sp[3];
            o0.x = bfpack(f0.x, f0.y); o0.y = bfpack(f0.z, f0.w);
            o0.z = bfpack(f1.x, f1.y); o0.w = bfpack(f1.z, f1.w);
            o1.x = bfpack(f2.x, f2.y); o1.y = bfpack(f2.z, f2.w);
            o1.z = bfpack(f3.x, f3.y); o1.w = bfpack(f3.z, f3.w);
        }
        *reinterpret_cast<uint4*>(&hs[g][c8 * 16])     = o0;
        *reinterpret_cast<uint4*>(&hs[g][c8 * 16 + 8]) = o1;
    }
    __syncthreads();   // sidx visible

    // ---- neighbor mean: 16 edges, fp8 rows (128 B), 16 B/lane, 4-deep pipeline ----
    {
        const int* si = &sidx[g * DEG];
        uint4 buf[4];
        #pragma unroll
        for (int e = 0; e < 4; ++e)
            buf[e] = *reinterpret_cast<const uint4*>(
                feat8 + (size_t)si[e] * INF + c8 * 16);

        float acc[16];
        #pragma unroll
        for (int i = 0; i < 16; ++i) acc[i] = 0.f;

        #pragma unroll
        for (int e = 0; e < DEG; ++e) {
            const uint4 v = buf[e & 3];
            if (e < DEG - 4)
                buf[e & 3] = *reinterpret_cast<const uint4*>(
                    feat8 + (size_t)si[e + 4] * INF + c8 * 16);
            const unsigned int w0 = v.x, w1 = v.y, w2 = v.z, w3 = v.w;
            {
                const f32x2 lo = __builtin_amdgcn_cvt_pk_f32_fp8(w0, false);
                const f32x2 hi = __builtin_amdgcn_cvt_pk_f32_fp8(w0, true);
                acc[0] += lo[0]; acc[1] += lo[1]; acc[2] += hi[0]; acc[3] += hi[1];
            }
            {
                const f32x2 lo = __builtin_amdgcn_cvt_pk_f32_fp8(w1, false);
                const f32x2 hi = __builtin_amdgcn_cvt_pk_f32_fp8(w1, true);
                acc[4] += lo[0]; acc[5] += lo[1]; acc[6] += hi[0]; acc[7] += hi[1];
            }
            {
                const f32x2 lo = __builtin_amdgcn_cvt_pk_f32_fp8(w2, false);
                const f32x2 hi = __builtin_amdgcn_cvt_pk_f32_fp8(w2, true);
                acc[8] += lo[0]; acc[9] += lo[1]; acc[10] += hi[0]; acc[11] += hi[1];
            }
            {
                const f32x2 lo = __builtin_amdgcn_cvt_pk_f32_fp8(w3, false);
                const f32x2 hi = __builtin_amdgcn_cvt_pk_f32_fp8(w3, true);
                acc[12] += lo[0]; acc[13] += lo[1]; acc[14] += hi[0]; acc[15] += hi[1];
            }
        }
        const float sc = 1.0f / (float)DEG;
        uint4 o0, o1;
        o0.x = bfpack(acc[0] * sc,  acc[1] * sc);
        o0.y = bfpack(acc[2] * sc,  acc[3] * sc);
        o0.z = bfpack(acc[4] * sc,  acc[5] * sc);
        o0.w = bfpack(acc[6] * sc,  acc[7] * sc);
        o1.x = bfpack(acc[8] * sc,  acc[9] * sc);
        o1.y = bfpack(acc[10] * sc, acc[11] * sc);
        o1.z = bfpack(acc[12] * sc, acc[13] * sc);
        o1.w = bfpack(acc[14] * sc, acc[15] * sc);
        *reinterpret_cast<uint4*>(&hs[g][INF + c8 * 16])     = o0;
        *reinterpret_cast<uint4*>(&hs[g][INF + c8 * 16 + 8]) = o1;
    }
    __syncthreads();   // hs complete

    // ---- MFMA GEMM: out[32][128] = hs(bf16) @ wB ----
    // wave wv: mtile = wv&1, u-tiles (wv>>1)*4 .. +3   (R3-verified layout)
    const int wv    = tid >> 6;
    const int lane  = tid & 63;
    const int l15   = lane & 15;
    const int lk    = lane >> 4;
    const int mtile = wv & 1;
    const int ubase = (wv >> 1) * 4;

    f32x4 acc0 = {0.f, 0.f, 0.f, 0.f};
    f32x4 acc1 = {0.f, 0.f, 0.f, 0.f};
    f32x4 acc2 = {0.f, 0.f, 0.f, 0.f};
    f32x4 acc3 = {0.f, 0.f, 0.f, 0.f};

    const unsigned short* arow = &hs[mtile * 16 + l15][lk * 8];
    #pragma unroll
    for (int t = 0; t < 8; ++t) {
        const short8 af = *reinterpret_cast<const short8*>(arow + t * 32);
        const unsigned short* wbt = wB + (((size_t)(t * 8 + ubase) * 64 + lane) << 3);
        const short8 b0 = *reinterpret_cast<const short8*>(wbt);
        const short8 b1 = *reinterpret_cast<const short8*>(wbt + 64 * 8);
        const short8 b2 = *reinterpret_cast<const short8*>(wbt + 2 * 64 * 8);
        const short8 b3 = *reinterpret_cast<const short8*>(wbt + 3 * 64 * 8);
        acc0 = __builtin_amdgcn_mfma_f32_16x16x32_bf16(af, b0, acc0, 0, 0, 0);
        acc1 = __builtin_amdgcn_mfma_f32_16x16x32_bf16(af, b1, acc1, 0, 0, 0);
        acc2 = __builtin_amdgcn_mfma_f32_16x16x32_bf16(af, b2, acc2, 0, 0, 0);
        acc3 = __builtin_amdgcn_mfma_f32_16x16x32_bf16(af, b3, acc3, 0, 0, 0);
    }

    // ---- epilogue: D row=(lane>>4)*4+reg -> node, col=u*16+(lane&15) ----
    const int nrow0 = base + mtile * 16 + lk * 4;
    #pragma unroll
    for (int i = 0; i < 4; ++i) {
        const int col = (ubase + i) * 16 + l15;
        const float bv = bias[col];
        const f32x4 a = (i == 0) ? acc0 : (i == 1) ? acc1 : (i == 2) ? acc2 : acc3;
        #pragma unroll
        for (int r = 0; r < 4; ++r) {
            const int nd = nrow0 + r;
            if (nd < NNODES)
                out[(size_t)nd * OUTF + col] = a[r] + bv;
        }
    }
}

// ================= fallback (fp32, used only if d_ws is tiny) =================
#define NB       32
#define HS_STRIDE 260
static __device__ __forceinline__ void add4(float4& a, const float4 b) {
    a.x += b.x; a.y += b.y; a.z += b.z; a.w += b.w;
}

__global__ __launch_bounds__(256)
void transpose_w(const float* __restrict__ w, float* __restrict__ wT) {
    const int idx = blockIdx.x * 256 + threadIdx.x;
    const int o = idx >> 8;
    const int k = idx & 255;
    wT[k * OUTF + o] = w[o * KDIM + k];
}

__global__ __launch_bounds__(NTHREADS, 4)
void sage_fused2(const float* __restrict__ feat,
                 const int*   __restrict__ off32,
                 const void*  __restrict__ indices_raw,
                 const float* __restrict__ wT,
                 const float* __restrict__ bias,
                 float*       __restrict__ out)
{
    __shared__ float hs[NB * HS_STRIDE];
    __shared__ int   sidx[NB * DEG];

    const int tid  = threadIdx.x;
    const int base = blockIdx.x * NB;
    const float4* feat4 = reinterpret_cast<const float4*>(feat);
    const bool idx64 = (off32[1] == 0 && off32[2] == DEG);
    const size_t ebase = (size_t)base * DEG;

    if (idx64) {
        const size_t e = ebase + 2 * (size_t)tid;
        int v0 = 0, v1 = 0;
        if (e + 1 < NEDGES) {
            const longlong2 p = *reinterpret_cast<const longlong2*>(
                reinterpret_cast<const long long*>(indices_raw) + e);
            v0 = (int)p.x; v1 = (int)p.y;
        }
        sidx[2 * tid] = v0; sidx[2 * tid + 1] = v1;
    } else if (tid < 128) {
        const size_t e = ebase + 4 * (size_t)tid;
        int4 v = make_int4(0, 0, 0, 0);
        if (e + 3 < NEDGES)
            v = *reinterpret_cast<const int4*>(reinterpret_cast<const int*>(indices_raw) + e);
        sidx[4 * tid] = v.x; sidx[4 * tid + 1] = v.y;
        sidx[4 * tid + 2] = v.z; sidx[4 * tid + 3] = v.w;
    }

    #pragma unroll
    for (int r = tid; r < NB * (INF / 4); r += NTHREADS) {
        const int n  = r >> 5;
        const int c4 = r & 31;
        const int node = base + n;
        float4 v = make_float4(0.f, 0.f, 0.f, 0.f);
        if (node < NNODES) v = feat4[(size_t)node * (INF / 4) + c4];
        *reinterpret_cast<float4*>(&hs[n * HS_STRIDE + c4 * 4]) = v;
    }
    __syncthreads();

    {
        const int gg  = tid >> 3;
        const int l8 = tid & 7;
        float4 a0 = make_float4(0,0,0,0), a1 = a0, a2 = a0, a3 = a0;
        const int* si = &sidx[gg * DEG];
        #pragma unroll
        for (int e = 0; e < DEG; ++e) {
            const int nbr = si[e];
            const float4* fr = feat4 + (size_t)nbr * (INF / 4);
            add4(a0, fr[l8]); add4(a1, fr[8 + l8]);
            add4(a2, fr[16 + l8]); add4(a3, fr[24 + l8]);
        }
        const float s = 1.0f / (float)DEG;
        float* hrow = &hs[gg * HS_STRIDE + INF];
        *reinterpret_cast<float4*>(&hrow[(0*8+l8)*4]) = make_float4(a0.x*s,a0.y*s,a0.z*s,a0.w*s);
        *reinterpret_cast<float4*>(&hrow[(1*8+l8)*4]) = make_float4(a1.x*s,a1.y*s,a1.z*s,a1.w*s);
        *reinterpret_cast<float4*>(&hrow[(2*8+l8)*4]) = make_float4(a2.x*s,a2.y*s,a2.z*s,a2.w*s);
        *reinterpret_cast<float4*>(&hrow[(3*8+l8)*4]) = make_float4(a3.x*s,a3.y*s,a3.z*s,a3.w*s);
    }
    __syncthreads();

    const int o4 = tid & 31;
    const int ng = tid >> 5;
    const float4* wT4 = reinterpret_cast<const float4*>(wT);
    float acc[4][4];
    #pragma unroll
    for (int i = 0; i < 4; ++i)
        #pragma unroll
        for (int j = 0; j < 4; ++j) acc[i][j] = 0.f;

    #pragma unroll 4
    for (int k4 = 0; k4 < KDIM / 4; ++k4) {
        const float4 w0 = wT4[(size_t)(4 * k4 + 0) * (OUTF / 4) + o4];
        const float4 w1 = wT4[(size_t)(4 * k4 + 1) * (OUTF / 4) + o4];
        const float4 w2 = wT4[(size_t)(4 * k4 + 2) * (OUTF / 4) + o4];
        const float4 w3 = wT4[(size_t)(4 * k4 + 3) * (OUTF / 4) + o4];
        #pragma unroll
        for (int i = 0; i < 4; ++i) {
            const float4 h = *reinterpret_cast<const float4*>(
                &hs[(ng * 4 + i) * HS_STRIDE + 4 * k4]);
            acc[i][0] += h.x*w0.x + h.y*w1.x + h.z*w2.x + h.w*w3.x;
            acc[i][1] += h.x*w0.y + h.y*w1.y + h.z*w2.y + h.w*w3.y;
            acc[i][2] += h.x*w0.z + h.y*w1.z + h.z*w2.z + h.w*w3.z;
            acc[i][3] += h.x*w0.w + h.y*w1.w + h.z*w2.w + h.w*w3.w;
        }
    }

    const float4 bv = *reinterpret_cast<const float4*>(&bias[o4 * 4]);
    #pragma unroll
    for (int i = 0; i < 4; ++i) {
        const int node = base + ng * 4 + i;
        if (node < NNODES) {
            float4 r;
            r.x = acc[i][0] + bv.x; r.y = acc[i][1] + bv.y;
            r.z = acc[i][2] + bv.z; r.w = acc[i][3] + bv.w;
            *reinterpret_cast<float4*>(&out[(size_t)node * OUTF + o4 * 4]) = r;
        }
    }
}

extern "C" void kernel_launch(void* const* d_in, const int* in_sizes, int n_in,
                              void* d_out, int out_size, void* d_ws, size_t ws_size,
                              hipStream_t stream) {
    const float* feat    = reinterpret_cast<const float*>(d_in[0]);
    const int*   off32   = reinterpret_cast<const int*>(d_in[1]);
    const void*  indices = d_in[2];
    const float* weight  = reinterpret_cast<const float*>(d_in[3]);
    const float* bias    = reinterpret_cast<const float*>(d_in[4]);
    float* out = reinterpret_cast<float*>(d_out);

    const size_t feat8_bytes = (size_t)NNODES * INF;                          // 6.4 MB
    const size_t wb_bytes    = (size_t)KDIM * OUTF * sizeof(unsigned short);  // 64 KB

    if (ws_size >= feat8_bytes + wb_bytes) {
        unsigned char*  feat8 = reinterpret_cast<unsigned char*>(d_ws);
        unsigned short* wB    = reinterpret_cast<unsigned short*>(
                                    reinterpret_cast<char*>(d_ws) + feat8_bytes);
        hipLaunchKernelGGL(prep, dim3(CONV_BLOCKS + PACK_BLOCKS), dim3(256), 0, stream,
                           feat, weight, feat8, wB);
        hipLaunchKernelGGL(sage_fp8, dim3(NBLK), dim3(NTHREADS), 0, stream,
                           feat, off32, indices, feat8, wB, bias, out);
    } else if (ws_size >= (size_t)KDIM * OUTF * sizeof(float)) {
        float* wT = reinterpret_cast<float*>(d_ws);
        hipLaunchKernelGGL(transpose_w, dim3((KDIM * OUTF) / 256), dim3(256), 0, stream,
                           weight, wT);
        hipLaunchKernelGGL(sage_fused2, dim3((NNODES + NB - 1) / NB), dim3(NTHREADS), 0, stream,
                           feat, off32, indices, wT, bias, out);
    }
}

// Round 6
// 95.930 us; speedup vs baseline: 1.0199x; 1.0199x over previous
//
#include <hip/hip_runtime.h>

#define NNODES   50000
#define DEG      16
#define NEDGES   (NNODES * DEG)
#define INF      128
#define OUTF     128
#define KDIM     256      // 2*IN_FEATS
#define NTHREADS 256

#define NBM      32       // nodes per main-kernel block
#define HSS      264      // hs row stride in bf16 (256 + 8 pad); 32*264*2 B = 16896 B
#define OBS      132      // epilogue float stride; 32*132*4 B = 16896 B (same buffer)
#define NBLK     ((NNODES + NBM - 1) / NBM)        // 1563
#define CONV_BLOCKS (NNODES * INF / 8 / 256)       // 3125
#define PACK_BLOCKS (KDIM * OUTF / 8 / 256)        // 16

// ---------------- helpers ----------------
static __device__ __forceinline__ unsigned int bfpack(float x, float y) {
    unsigned int ux = __float_as_uint(x), uy = __float_as_uint(y);
    ux = (ux + 0x7fffu + ((ux >> 16) & 1u)) >> 16;
    uy = (uy + 0x7fffu + ((uy >> 16) & 1u)) >> 16;
    return ux | (uy << 16);
}
typedef __attribute__((ext_vector_type(8))) short short8;
typedef __attribute__((ext_vector_type(4))) float f32x4;
typedef __attribute__((ext_vector_type(2))) float f32x2;

// pack 4 f32 -> 4 fp8 e4m3 (one uint)
static __device__ __forceinline__ unsigned int fp8pack4(float a, float b, float c, float d) {
    int w = __builtin_amdgcn_cvt_pk_fp8_f32(a, b, 0, false);
    w = __builtin_amdgcn_cvt_pk_fp8_f32(c, d, w, true);
    return (unsigned int)w;
}

// ---------------- prep: feat f32 -> {bf16, fp8}  +  W -> B-fragment bf16 pack ----------------
// wB[t][u][lane][j] = W[u*16 + (lane&15)][t*32 + (lane>>4)*8 + j]
__global__ __launch_bounds__(256)
void prep(const float* __restrict__ feat, const float* __restrict__ weight,
          unsigned short* __restrict__ featb, unsigned char* __restrict__ feat8,
          unsigned short* __restrict__ wB) {
    const int bid = blockIdx.x;
    const int tid = threadIdx.x;
    if (bid < CONV_BLOCKS) {
        const int gid = bid * 256 + tid;               // 8 floats each
        const float4* src = reinterpret_cast<const float4*>(feat + (size_t)gid * 8);
        const float4 f0 = src[0];
        const float4 f1 = src[1];
        uint4 ob;
        ob.x = bfpack(f0.x, f0.y); ob.y = bfpack(f0.z, f0.w);
        ob.z = bfpack(f1.x, f1.y); ob.w = bfpack(f1.z, f1.w);
        *reinterpret_cast<uint4*>(featb + (size_t)gid * 8) = ob;
        uint2 o8;
        o8.x = fp8pack4(f0.x, f0.y, f0.z, f0.w);
        o8.y = fp8pack4(f1.x, f1.y, f1.z, f1.w);
        *reinterpret_cast<uint2*>(feat8 + (size_t)gid * 8) = o8;
    } else {
        const int gid = (bid - CONV_BLOCKS) * 256 + tid;   // 4096 groups of 8
        const int lane = gid & 63;
        const int u    = (gid >> 6) & 7;
        const int t    = gid >> 9;
        const int row  = u * 16 + (lane & 15);
        const int kb   = t * 32 + (lane >> 4) * 8;
        const float* src = weight + (size_t)row * KDIM + kb;
        const float4 f0 = *reinterpret_cast<const float4*>(src);
        const float4 f1 = *reinterpret_cast<const float4*>(src + 4);
        uint4 o;
        o.x = bfpack(f0.x, f0.y); o.y = bfpack(f0.z, f0.w);
        o.z = bfpack(f1.x, f1.y); o.w = bfpack(f1.z, f1.w);
        *reinterpret_cast<uint4*>(wB + (size_t)gid * 8) = o;
    }
}

// ---------------- main: fp8 gather + bf16 MFMA GEMM + coalesced LDS epilogue ----------------
__global__ __launch_bounds__(NTHREADS, 6)
void sage_v6(const unsigned short* __restrict__ featb,
             const int*   __restrict__ off32,
             const void*  __restrict__ indices_raw,
             const unsigned char* __restrict__ feat8,
             const unsigned short* __restrict__ wB,
             const float* __restrict__ bias,
             float*       __restrict__ out)
{
    __shared__ unsigned short hs[NBM][HSS];   // 16896 B; reused as float[32][132] in epilogue
    __shared__ int sidx[NBM * DEG];           // 2 KB

    const int tid  = threadIdx.x;
    const int base = blockIdx.x * NBM;
    const size_t ebase = (size_t)base * DEG;

    const bool idx64 = (off32[1] == 0 && off32[2] == DEG);

    // ---- stage 512 indices into LDS (OOB slots -> 0, safe dummy) ----
    if (idx64) {
        const size_t e = ebase + 2 * (size_t)tid;
        int v0 = 0, v1 = 0;
        if (e + 1 < NEDGES) {
            const longlong2 p = *reinterpret_cast<const longlong2*>(
                reinterpret_cast<const long long*>(indices_raw) + e);
            v0 = (int)p.x; v1 = (int)p.y;
        }
        sidx[2 * tid]     = v0;
        sidx[2 * tid + 1] = v1;
    } else if (tid < 128) {
        const size_t e = ebase + 4 * (size_t)tid;
        int4 v = make_int4(0, 0, 0, 0);
        if (e + 3 < NEDGES)
            v = *reinterpret_cast<const int4*>(
                reinterpret_cast<const int*>(indices_raw) + e);
        sidx[4 * tid] = v.x; sidx[4 * tid + 1] = v.y;
        sidx[4 * tid + 2] = v.z; sidx[4 * tid + 3] = v.w;
    }

    const int g    = tid >> 3;    // local node 0..31
    const int c8   = tid & 7;     // 16-column slice 0..7
    const int node = base + g;

    // ---- self features: 16 bf16 from featb (two uint4 = 32 B/lane, coalesced) ----
    {
        uint4 s0 = make_uint4(0, 0, 0, 0), s1 = s0;
        if (node < NNODES) {
            const uint4* sp = reinterpret_cast<const uint4*>(
                featb + (size_t)node * INF + c8 * 16);
            s0 = sp[0]; s1 = sp[1];
        }
        *reinterpret_cast<uint4*>(&hs[g][c8 * 16])     = s0;
        *reinterpret_cast<uint4*>(&hs[g][c8 * 16 + 8]) = s1;
    }
    __syncthreads();   // sidx visible

    // ---- neighbor mean: 16 edges, fp8 rows (128 B), 16 B/lane, 4-deep pipeline ----
    {
        const int* si = &sidx[g * DEG];
        uint4 buf[4];
        #pragma unroll
        for (int e = 0; e < 4; ++e)
            buf[e] = *reinterpret_cast<const uint4*>(
                feat8 + (size_t)si[e] * INF + c8 * 16);

        float acc[16];
        #pragma unroll
        for (int i = 0; i < 16; ++i) acc[i] = 0.f;

        #pragma unroll
        for (int e = 0; e < DEG; ++e) {
            const uint4 v = buf[e & 3];
            if (e < DEG - 4)
                buf[e & 3] = *reinterpret_cast<const uint4*>(
                    feat8 + (size_t)si[e + 4] * INF + c8 * 16);
            const unsigned int w0 = v.x, w1 = v.y, w2 = v.z, w3 = v.w;
            {
                const f32x2 lo = __builtin_amdgcn_cvt_pk_f32_fp8(w0, false);
                const f32x2 hi = __builtin_amdgcn_cvt_pk_f32_fp8(w0, true);
                acc[0] += lo[0]; acc[1] += lo[1]; acc[2] += hi[0]; acc[3] += hi[1];
            }
            {
                const f32x2 lo = __builtin_amdgcn_cvt_pk_f32_fp8(w1, false);
                const f32x2 hi = __builtin_amdgcn_cvt_pk_f32_fp8(w1, true);
                acc[4] += lo[0]; acc[5] += lo[1]; acc[6] += hi[0]; acc[7] += hi[1];
            }
            {
                const f32x2 lo = __builtin_amdgcn_cvt_pk_f32_fp8(w2, false);
                const f32x2 hi = __builtin_amdgcn_cvt_pk_f32_fp8(w2, true);
                acc[8] += lo[0]; acc[9] += lo[1]; acc[10] += hi[0]; acc[11] += hi[1];
            }
            {
                const f32x2 lo = __builtin_amdgcn_cvt_pk_f32_fp8(w3, false);
                const f32x2 hi = __builtin_amdgcn_cvt_pk_f32_fp8(w3, true);
                acc[12] += lo[0]; acc[13] += lo[1]; acc[14] += hi[0]; acc[15] += hi[1];
            }
        }
        const float sc = 1.0f / (float)DEG;
        uint4 o0, o1;
        o0.x = bfpack(acc[0] * sc,  acc[1] * sc);
        o0.y = bfpack(acc[2] * sc,  acc[3] * sc);
        o0.z = bfpack(acc[4] * sc,  acc[5] * sc);
        o0.w = bfpack(acc[6] * sc,  acc[7] * sc);
        o1.x = bfpack(acc[8] * sc,  acc[9] * sc);
        o1.y = bfpack(acc[10] * sc, acc[11] * sc);
        o1.z = bfpack(acc[12] * sc, acc[13] * sc);
        o1.w = bfpack(acc[14] * sc, acc[15] * sc);
        *reinterpret_cast<uint4*>(&hs[g][INF + c8 * 16])     = o0;
        *reinterpret_cast<uint4*>(&hs[g][INF + c8 * 16 + 8]) = o1;
    }
    __syncthreads();   // hs complete

    // ---- MFMA GEMM: out[32][128] = hs(bf16) @ wB ----
    // wave wv: mtile = wv&1, u-tiles (wv>>1)*4 .. +3
    const int wv    = tid >> 6;
    const int lane  = tid & 63;
    const int l15   = lane & 15;
    const int lk    = lane >> 4;
    const int mtile = wv & 1;
    const int ubase = (wv >> 1) * 4;

    f32x4 acc0 = {0.f, 0.f, 0.f, 0.f};
    f32x4 acc1 = {0.f, 0.f, 0.f, 0.f};
    f32x4 acc2 = {0.f, 0.f, 0.f, 0.f};
    f32x4 acc3 = {0.f, 0.f, 0.f, 0.f};

    const unsigned short* arow = &hs[mtile * 16 + l15][lk * 8];
    #pragma unroll
    for (int t = 0; t < 8; ++t) {
        const short8 af = *reinterpret_cast<const short8*>(arow + t * 32);
        const unsigned short* wbt = wB + (((size_t)(t * 8 + ubase) * 64 + lane) << 3);
        const short8 b0 = *reinterpret_cast<const short8*>(wbt);
        const short8 b1 = *reinterpret_cast<const short8*>(wbt + 64 * 8);
        const short8 b2 = *reinterpret_cast<const short8*>(wbt + 2 * 64 * 8);
        const short8 b3 = *reinterpret_cast<const short8*>(wbt + 3 * 64 * 8);
        acc0 = __builtin_amdgcn_mfma_f32_16x16x32_bf16(af, b0, acc0, 0, 0, 0);
        acc1 = __builtin_amdgcn_mfma_f32_16x16x32_bf16(af, b1, acc1, 0, 0, 0);
        acc2 = __builtin_amdgcn_mfma_f32_16x16x32_bf16(af, b2, acc2, 0, 0, 0);
        acc3 = __builtin_amdgcn_mfma_f32_16x16x32_bf16(af, b3, acc3, 0, 0, 0);
    }
    __syncthreads();   // all hs reads done; safe to overwrite LDS

    // ---- epilogue 1: acc -> LDS float[32][132] (2-way bank alias only = free) ----
    float* ob = reinterpret_cast<float*>(&hs[0][0]);
    {
        const int row0 = mtile * 16 + lk * 4;
        const int colb = ubase * 16 + l15;
        #pragma unroll
        for (int i = 0; i < 4; ++i) {
            const f32x4 a = (i == 0) ? acc0 : (i == 1) ? acc1 : (i == 2) ? acc2 : acc3;
            #pragma unroll
            for (int r = 0; r < 4; ++r)
                ob[(row0 + r) * OBS + colb + i * 16] = a[r];
        }
    }
    __syncthreads();

    // ---- epilogue 2: coalesced float4 stores (+bias), 1 KB per wave-instruction ----
    {
        float4* out4 = reinterpret_cast<float4*>(out);
        const float4* bias4 = reinterpret_cast<const float4*>(bias);
        #pragma unroll
        for (int it = 0; it < 4; ++it) {
            const int idx = it * NTHREADS + tid;    // 0..1023
            const int row = idx >> 5;               // 0..31
            const int c4  = idx & 31;               // float4 col 0..31
            const int nd  = base + row;
            if (nd < NNODES) {
                const float4 v = *reinterpret_cast<const float4*>(&ob[row * OBS + c4 * 4]);
                const float4 b = bias4[c4];
                float4 r;
                r.x = v.x + b.x; r.y = v.y + b.y; r.z = v.z + b.z; r.w = v.w + b.w;
                out4[(size_t)nd * (OUTF / 4) + c4] = r;
            }
        }
    }
}

// ================= fallback (fp32, used only if d_ws is tiny) =================
#define NB       32
#define HS_STRIDE 260
static __device__ __forceinline__ void add4(float4& a, const float4 b) {
    a.x += b.x; a.y += b.y; a.z += b.z; a.w += b.w;
}

__global__ __launch_bounds__(256)
void transpose_w(const float* __restrict__ w, float* __restrict__ wT) {
    const int idx = blockIdx.x * 256 + threadIdx.x;
    const int o = idx >> 8;
    const int k = idx & 255;
    wT[k * OUTF + o] = w[o * KDIM + k];
}

__global__ __launch_bounds__(NTHREADS, 4)
void sage_fused2(const float* __restrict__ feat,
                 const int*   __restrict__ off32,
                 const void*  __restrict__ indices_raw,
                 const float* __restrict__ wT,
                 const float* __restrict__ bias,
                 float*       __restrict__ out)
{
    __shared__ float hs[NB * HS_STRIDE];
    __shared__ int   sidx[NB * DEG];

    const int tid  = threadIdx.x;
    const int base = blockIdx.x * NB;
    const float4* feat4 = reinterpret_cast<const float4*>(feat);
    const bool idx64 = (off32[1] == 0 && off32[2] == DEG);
    const size_t ebase = (size_t)base * DEG;

    if (idx64) {
        const size_t e = ebase + 2 * (size_t)tid;
        int v0 = 0, v1 = 0;
        if (e + 1 < NEDGES) {
            const longlong2 p = *reinterpret_cast<const longlong2*>(
                reinterpret_cast<const long long*>(indices_raw) + e);
            v0 = (int)p.x; v1 = (int)p.y;
        }
        sidx[2 * tid] = v0; sidx[2 * tid + 1] = v1;
    } else if (tid < 128) {
        const size_t e = ebase + 4 * (size_t)tid;
        int4 v = make_int4(0, 0, 0, 0);
        if (e + 3 < NEDGES)
            v = *reinterpret_cast<const int4*>(reinterpret_cast<const int*>(indices_raw) + e);
        sidx[4 * tid] = v.x; sidx[4 * tid + 1] = v.y;
        sidx[4 * tid + 2] = v.z; sidx[4 * tid + 3] = v.w;
    }

    #pragma unroll
    for (int r = tid; r < NB * (INF / 4); r += NTHREADS) {
        const int n  = r >> 5;
        const int c4 = r & 31;
        const int node = base + n;
        float4 v = make_float4(0.f, 0.f, 0.f, 0.f);
        if (node < NNODES) v = feat4[(size_t)node * (INF / 4) + c4];
        *reinterpret_cast<float4*>(&hs[n * HS_STRIDE + c4 * 4]) = v;
    }
    __syncthreads();

    {
        const int gg  = tid >> 3;
        const int l8 = tid & 7;
        float4 a0 = make_float4(0,0,0,0), a1 = a0, a2 = a0, a3 = a0;
        const int* si = &sidx[gg * DEG];
        #pragma unroll
        for (int e = 0; e < DEG; ++e) {
            const int nbr = si[e];
            const float4* fr = feat4 + (size_t)nbr * (INF / 4);
            add4(a0, fr[l8]); add4(a1, fr[8 + l8]);
            add4(a2, fr[16 + l8]); add4(a3, fr[24 + l8]);
        }
        const float s = 1.0f / (float)DEG;
        float* hrow = &hs[gg * HS_STRIDE + INF];
        *reinterpret_cast<float4*>(&hrow[(0*8+l8)*4]) = make_float4(a0.x*s,a0.y*s,a0.z*s,a0.w*s);
        *reinterpret_cast<float4*>(&hrow[(1*8+l8)*4]) = make_float4(a1.x*s,a1.y*s,a1.z*s,a1.w*s);
        *reinterpret_cast<float4*>(&hrow[(2*8+l8)*4]) = make_float4(a2.x*s,a2.y*s,a2.z*s,a2.w*s);
        *reinterpret_cast<float4*>(&hrow[(3*8+l8)*4]) = make_float4(a3.x*s,a3.y*s,a3.z*s,a3.w*s);
    }
    __syncthreads();

    const int o4 = tid & 31;
    const int ng = tid >> 5;
    const float4* wT4 = reinterpret_cast<const float4*>(wT);
    float acc[4][4];
    #pragma unroll
    for (int i = 0; i < 4; ++i)
        #pragma unroll
        for (int j = 0; j < 4; ++j) acc[i][j] = 0.f;

    #pragma unroll 4
    for (int k4 = 0; k4 < KDIM / 4; ++k4) {
        const float4 w0 = wT4[(size_t)(4 * k4 + 0) * (OUTF / 4) + o4];
        const float4 w1 = wT4[(size_t)(4 * k4 + 1) * (OUTF / 4) + o4];
        const float4 w2 = wT4[(size_t)(4 * k4 + 2) * (OUTF / 4) + o4];
        const float4 w3 = wT4[(size_t)(4 * k4 + 3) * (OUTF / 4) + o4];
        #pragma unroll
        for (int i = 0; i < 4; ++i) {
            const float4 h = *reinterpret_cast<const float4*>(
                &hs[(ng * 4 + i) * HS_STRIDE + 4 * k4]);
            acc[i][0] += h.x*w0.x + h.y*w1.x + h.z*w2.x + h.w*w3.x;
            acc[i][1] += h.x*w0.y + h.y*w1.y + h.z*w2.y + h.w*w3.y;
            acc[i][2] += h.x*w0.z + h.y*w1.z + h.z*w2.z + h.w*w3.z;
            acc[i][3] += h.x*w0.w + h.y*w1.w + h.z*w2.w + h.w*w3.w;
        }
    }

    const float4 bv = *reinterpret_cast<const float4*>(&bias[o4 * 4]);
    #pragma unroll
    for (int i = 0; i < 4; ++i) {
        const int node = base + ng * 4 + i;
        if (node < NNODES) {
            float4 r;
            r.x = acc[i][0] + bv.x; r.y = acc[i][1] + bv.y;
            r.z = acc[i][2] + bv.z; r.w = acc[i][3] + bv.w;
            *reinterpret_cast<float4*>(&out[(size_t)node * OUTF + o4 * 4]) = r;
        }
    }
}

extern "C" void kernel_launch(void* const* d_in, const int* in_sizes, int n_in,
                              void* d_out, int out_size, void* d_ws, size_t ws_size,
                              hipStream_t stream) {
    const float* feat    = reinterpret_cast<const float*>(d_in[0]);
    const int*   off32   = reinterpret_cast<const int*>(d_in[1]);
    const void*  indices = d_in[2];
    const float* weight  = reinterpret_cast<const float*>(d_in[3]);
    const float* bias    = reinterpret_cast<const float*>(d_in[4]);
    float* out = reinterpret_cast<float*>(d_out);

    const size_t featb_bytes = (size_t)NNODES * INF * sizeof(unsigned short); // 12.8 MB
    const size_t feat8_bytes = (size_t)NNODES * INF;                          // 6.4 MB
    const size_t wb_bytes    = (size_t)KDIM * OUTF * sizeof(unsigned short);  // 64 KB

    if (ws_size >= featb_bytes + feat8_bytes + wb_bytes) {
        char* ws = reinterpret_cast<char*>(d_ws);
        unsigned short* featb = reinterpret_cast<unsigned short*>(ws);
        unsigned char*  feat8 = reinterpret_cast<unsigned char*>(ws + featb_bytes);
        unsigned short* wB    = reinterpret_cast<unsigned short*>(ws + featb_bytes + feat8_bytes);
        hipLaunchKernelGGL(prep, dim3(CONV_BLOCKS + PACK_BLOCKS), dim3(256), 0, stream,
                           feat, weight, featb, feat8, wB);
        hipLaunchKernelGGL(sage_v6, dim3(NBLK), dim3(NTHREADS), 0, stream,
                           featb, off32, indices, feat8, wB, bias, out);
    } else if (ws_size >= (size_t)KDIM * OUTF * sizeof(float)) {
        float* wT = reinterpret_cast<float*>(d_ws);
        hipLaunchKernelGGL(transpose_w, dim3((KDIM * OUTF) / 256), dim3(256), 0, stream,
                           weight, wT);
        hipLaunchKernelGGL(sage_fused2, dim3((NNODES + NB - 1) / NB), dim3(NTHREADS), 0, stream,
                           feat, off32, indices, wT, bias, out);
    }
}

// Round 7
// 43.892 us; speedup vs baseline: 2.2290x; 2.1856x over previous
//
#include <hip/hip_runtime.h>

#define NNODES   50000
#define DEG      16
#define NEDGES   (NNODES * DEG)
#define INF      128
#define OUTF     128
#define KDIM     256      // 2*IN_FEATS
#define NTHREADS 256

#define NBM      32       // nodes per main-kernel block
#define HSS      264      // hs row stride in bf16 (256 + 8 pad); 32*264*2 B = 16896 B
#define OBS      132      // epilogue float stride; 32*132*4 B = 16896 B (same buffer)
#define NBLK     ((NNODES + NBM - 1) / NBM)        // 1563
#define CONV_BLOCKS (NNODES * INF / 8 / 256)       // 3125
#define PACK_BLOCKS (KDIM * OUTF / 8 / 256)        // 16

// ---------------- helpers ----------------
static __device__ __forceinline__ unsigned int bfpack(float x, float y) {
    unsigned int ux = __float_as_uint(x), uy = __float_as_uint(y);
    ux = (ux + 0x7fffu + ((ux >> 16) & 1u)) >> 16;
    uy = (uy + 0x7fffu + ((uy >> 16) & 1u)) >> 16;
    return ux | (uy << 16);
}
static __device__ __forceinline__ float bflo(unsigned int u) { return __uint_as_float(u << 16); }
static __device__ __forceinline__ float bfhi(unsigned int u) { return __uint_as_float(u & 0xffff0000u); }

typedef __attribute__((ext_vector_type(8))) short short8;
typedef __attribute__((ext_vector_type(4))) float f32x4;

// ---------------- prep: feat f32 -> bf16  +  W -> B-fragment bf16 pack ----------------
// wB[t][u][lane][j] = W[u*16 + (lane&15)][t*32 + (lane>>4)*8 + j]
__global__ __launch_bounds__(256)
void prep(const float* __restrict__ feat, const float* __restrict__ weight,
          unsigned short* __restrict__ featb, unsigned short* __restrict__ wB) {
    const int bid = blockIdx.x;
    const int tid = threadIdx.x;
    if (bid < CONV_BLOCKS) {
        const int gid = bid * 256 + tid;               // 8 floats each
        const float4* src = reinterpret_cast<const float4*>(feat + (size_t)gid * 8);
        const float4 f0 = src[0];
        const float4 f1 = src[1];
        uint4 ob;
        ob.x = bfpack(f0.x, f0.y); ob.y = bfpack(f0.z, f0.w);
        ob.z = bfpack(f1.x, f1.y); ob.w = bfpack(f1.z, f1.w);
        *reinterpret_cast<uint4*>(featb + (size_t)gid * 8) = ob;
    } else {
        const int gid = (bid - CONV_BLOCKS) * 256 + tid;   // 4096 groups of 8
        const int lane = gid & 63;
        const int u    = (gid >> 6) & 7;
        const int t    = gid >> 9;
        const int row  = u * 16 + (lane & 15);
        const int kb   = t * 32 + (lane >> 4) * 8;
        const float* src = weight + (size_t)row * KDIM + kb;
        const float4 f0 = *reinterpret_cast<const float4*>(src);
        const float4 f1 = *reinterpret_cast<const float4*>(src + 4);
        uint4 o;
        o.x = bfpack(f0.x, f0.y); o.y = bfpack(f0.z, f0.w);
        o.z = bfpack(f1.x, f1.y); o.w = bfpack(f1.z, f1.w);
        *reinterpret_cast<uint4*>(wB + (size_t)gid * 8) = o;
    }
}

// ---------------- main: bf16 gather + bf16 MFMA GEMM + coalesced LDS epilogue ----------------
__global__ __launch_bounds__(NTHREADS, 6)
void sage_v7(const unsigned short* __restrict__ featb,
             const int*   __restrict__ off32,
             const void*  __restrict__ indices_raw,
             const unsigned short* __restrict__ wB,
             const float* __restrict__ bias,
             float*       __restrict__ out)
{
    __shared__ unsigned short hs[NBM][HSS];   // 16896 B; reused as float[32][132] in epilogue
    __shared__ int sidx[NBM * DEG];           // 2 KB

    const int tid  = threadIdx.x;
    const int base = blockIdx.x * NBM;
    const size_t ebase = (size_t)base * DEG;

    const bool idx64 = (off32[1] == 0 && off32[2] == DEG);

    // ---- stage 512 indices into LDS (OOB slots -> 0, safe dummy) ----
    if (idx64) {
        const size_t e = ebase + 2 * (size_t)tid;
        int v0 = 0, v1 = 0;
        if (e + 1 < NEDGES) {
            const longlong2 p = *reinterpret_cast<const longlong2*>(
                reinterpret_cast<const long long*>(indices_raw) + e);
            v0 = (int)p.x; v1 = (int)p.y;
        }
        sidx[2 * tid]     = v0;
        sidx[2 * tid + 1] = v1;
    } else if (tid < 128) {
        const size_t e = ebase + 4 * (size_t)tid;
        int4 v = make_int4(0, 0, 0, 0);
        if (e + 3 < NEDGES)
            v = *reinterpret_cast<const int4*>(
                reinterpret_cast<const int*>(indices_raw) + e);
        sidx[4 * tid] = v.x; sidx[4 * tid + 1] = v.y;
        sidx[4 * tid + 2] = v.z; sidx[4 * tid + 3] = v.w;
    }
    __syncthreads();   // sidx visible

    // ---- gather + mean: 16 lanes/node (16B bf16 slice), 2 passes, 8-deep pipeline ----
    const int c = tid & 15;            // 16B slice: bf16 columns [c*8, c*8+8)
    {
        const float sc = 1.0f / (float)DEG;
        #pragma unroll
        for (int p = 0; p < 2; ++p) {
            const int g    = p * 16 + (tid >> 4);   // local node 0..31
            const int node = base + g;

            // self feature slice -> hs[g][c*8]  (coalesced 16B/lane from featb)
            uint4 sv = make_uint4(0, 0, 0, 0);
            if (node < NNODES)
                sv = *reinterpret_cast<const uint4*>(featb + (size_t)node * INF + c * 8);
            *reinterpret_cast<uint4*>(&hs[g][c * 8]) = sv;

            // neighbor mean slice, 8-deep explicit pipeline
            const int* si = &sidx[g * DEG];
            uint4 buf[8];
            #pragma unroll
            for (int e = 0; e < 8; ++e)
                buf[e] = *reinterpret_cast<const uint4*>(
                    featb + (size_t)si[e] * INF + c * 8);

            float a0 = 0.f, a1 = 0.f, a2 = 0.f, a3 = 0.f;
            float a4 = 0.f, a5 = 0.f, a6 = 0.f, a7 = 0.f;
            #pragma unroll
            for (int e = 0; e < DEG; ++e) {
                const uint4 v = buf[e & 7];
                if (e < DEG - 8)
                    buf[e & 7] = *reinterpret_cast<const uint4*>(
                        featb + (size_t)si[e + 8] * INF + c * 8);
                a0 += bflo(v.x); a1 += bfhi(v.x);
                a2 += bflo(v.y); a3 += bfhi(v.y);
                a4 += bflo(v.z); a5 += bfhi(v.z);
                a6 += bflo(v.w); a7 += bfhi(v.w);
            }
            uint4 o;
            o.x = bfpack(a0 * sc, a1 * sc);
            o.y = bfpack(a2 * sc, a3 * sc);
            o.z = bfpack(a4 * sc, a5 * sc);
            o.w = bfpack(a6 * sc, a7 * sc);
            *reinterpret_cast<uint4*>(&hs[g][INF + c * 8]) = o;
        }
    }
    __syncthreads();   // hs complete

    // ---- MFMA GEMM: out[32][128] = hs(bf16) @ wB ----
    // wave wv: mtile = wv&1, u-tiles (wv>>1)*4 .. +3   (R3-verified layout)
    const int wv    = tid >> 6;
    const int lane  = tid & 63;
    const int l15   = lane & 15;
    const int lk    = lane >> 4;
    const int mtile = wv & 1;
    const int ubase = (wv >> 1) * 4;

    f32x4 acc0 = {0.f, 0.f, 0.f, 0.f};
    f32x4 acc1 = {0.f, 0.f, 0.f, 0.f};
    f32x4 acc2 = {0.f, 0.f, 0.f, 0.f};
    f32x4 acc3 = {0.f, 0.f, 0.f, 0.f};

    const unsigned short* arow = &hs[mtile * 16 + l15][lk * 8];
    #pragma unroll
    for (int t = 0; t < 8; ++t) {
        const short8 af = *reinterpret_cast<const short8*>(arow + t * 32);
        const unsigned short* wbt = wB + (((size_t)(t * 8 + ubase) * 64 + lane) << 3);
        const short8 b0 = *reinterpret_cast<const short8*>(wbt);
        const short8 b1 = *reinterpret_cast<const short8*>(wbt + 64 * 8);
        const short8 b2 = *reinterpret_cast<const short8*>(wbt + 2 * 64 * 8);
        const short8 b3 = *reinterpret_cast<const short8*>(wbt + 3 * 64 * 8);
        acc0 = __builtin_amdgcn_mfma_f32_16x16x32_bf16(af, b0, acc0, 0, 0, 0);
        acc1 = __builtin_amdgcn_mfma_f32_16x16x32_bf16(af, b1, acc1, 0, 0, 0);
        acc2 = __builtin_amdgcn_mfma_f32_16x16x32_bf16(af, b2, acc2, 0, 0, 0);
        acc3 = __builtin_amdgcn_mfma_f32_16x16x32_bf16(af, b3, acc3, 0, 0, 0);
    }
    __syncthreads();   // all hs reads done; safe to overwrite LDS

    // ---- epilogue 1: acc -> LDS float[32][132] ----
    float* ob = reinterpret_cast<float*>(&hs[0][0]);
    {
        const int row0 = mtile * 16 + lk * 4;
        const int colb = ubase * 16 + l15;
        #pragma unroll
        for (int i = 0; i < 4; ++i) {
            const f32x4 a = (i == 0) ? acc0 : (i == 1) ? acc1 : (i == 2) ? acc2 : acc3;
            #pragma unroll
            for (int r = 0; r < 4; ++r)
                ob[(row0 + r) * OBS + colb + i * 16] = a[r];
        }
    }
    __syncthreads();

    // ---- epilogue 2: coalesced float4 stores (+bias), 1 KB per wave-instruction ----
    {
        float4* out4 = reinterpret_cast<float4*>(out);
        const float4* bias4 = reinterpret_cast<const float4*>(bias);
        #pragma unroll
        for (int it = 0; it < 4; ++it) {
            const int idx = it * NTHREADS + tid;    // 0..1023
            const int row = idx >> 5;               // 0..31
            const int c4  = idx & 31;               // float4 col 0..31
            const int nd  = base + row;
            if (nd < NNODES) {
                const float4 v = *reinterpret_cast<const float4*>(&ob[row * OBS + c4 * 4]);
                const float4 b = bias4[c4];
                float4 r;
                r.x = v.x + b.x; r.y = v.y + b.y; r.z = v.z + b.z; r.w = v.w + b.w;
                out4[(size_t)nd * (OUTF / 4) + c4] = r;
            }
        }
    }
}

// ================= fallback (fp32, used only if d_ws is tiny) =================
#define NB       32
#define HS_STRIDE 260
static __device__ __forceinline__ void add4(float4& a, const float4 b) {
    a.x += b.x; a.y += b.y; a.z += b.z; a.w += b.w;
}

__global__ __launch_bounds__(256)
void transpose_w(const float* __restrict__ w, float* __restrict__ wT) {
    const int idx = blockIdx.x * 256 + threadIdx.x;
    const int o = idx >> 8;
    const int k = idx & 255;
    wT[k * OUTF + o] = w[o * KDIM + k];
}

__global__ __launch_bounds__(NTHREADS, 4)
void sage_fused2(const float* __restrict__ feat,
                 const int*   __restrict__ off32,
                 const void*  __restrict__ indices_raw,
                 const float* __restrict__ wT,
                 const float* __restrict__ bias,
                 float*       __restrict__ out)
{
    __shared__ float hs[NB * HS_STRIDE];
    __shared__ int   sidx[NB * DEG];

    const int tid  = threadIdx.x;
    const int base = blockIdx.x * NB;
    const float4* feat4 = reinterpret_cast<const float4*>(feat);
    const bool idx64 = (off32[1] == 0 && off32[2] == DEG);
    const size_t ebase = (size_t)base * DEG;

    if (idx64) {
        const size_t e = ebase + 2 * (size_t)tid;
        int v0 = 0, v1 = 0;
        if (e + 1 < NEDGES) {
            const longlong2 p = *reinterpret_cast<const longlong2*>(
                reinterpret_cast<const long long*>(indices_raw) + e);
            v0 = (int)p.x; v1 = (int)p.y;
        }
        sidx[2 * tid] = v0; sidx[2 * tid + 1] = v1;
    } else if (tid < 128) {
        const size_t e = ebase + 4 * (size_t)tid;
        int4 v = make_int4(0, 0, 0, 0);
        if (e + 3 < NEDGES)
            v = *reinterpret_cast<const int4*>(reinterpret_cast<const int*>(indices_raw) + e);
        sidx[4 * tid] = v.x; sidx[4 * tid + 1] = v.y;
        sidx[4 * tid + 2] = v.z; sidx[4 * tid + 3] = v.w;
    }

    #pragma unroll
    for (int r = tid; r < NB * (INF / 4); r += NTHREADS) {
        const int n  = r >> 5;
        const int c4 = r & 31;
        const int node = base + n;
        float4 v = make_float4(0.f, 0.f, 0.f, 0.f);
        if (node < NNODES) v = feat4[(size_t)node * (INF / 4) + c4];
        *reinterpret_cast<float4*>(&hs[n * HS_STRIDE + c4 * 4]) = v;
    }
    __syncthreads();

    {
        const int gg  = tid >> 3;
        const int l8 = tid & 7;
        float4 a0 = make_float4(0,0,0,0), a1 = a0, a2 = a0, a3 = a0;
        const int* si = &sidx[gg * DEG];
        #pragma unroll
        for (int e = 0; e < DEG; ++e) {
            const int nbr = si[e];
            const float4* fr = feat4 + (size_t)nbr * (INF / 4);
            add4(a0, fr[l8]); add4(a1, fr[8 + l8]);
            add4(a2, fr[16 + l8]); add4(a3, fr[24 + l8]);
        }
        const float s = 1.0f / (float)DEG;
        float* hrow = &hs[gg * HS_STRIDE + INF];
        *reinterpret_cast<float4*>(&hrow[(0*8+l8)*4]) = make_float4(a0.x*s,a0.y*s,a0.z*s,a0.w*s);
        *reinterpret_cast<float4*>(&hrow[(1*8+l8)*4]) = make_float4(a1.x*s,a1.y*s,a1.z*s,a1.w*s);
        *reinterpret_cast<float4*>(&hrow[(2*8+l8)*4]) = make_float4(a2.x*s,a2.y*s,a2.z*s,a2.w*s);
        *reinterpret_cast<float4*>(&hrow[(3*8+l8)*4]) = make_float4(a3.x*s,a3.y*s,a3.z*s,a3.w*s);
    }
    __syncthreads();

    const int o4 = tid & 31;
    const int ng = tid >> 5;
    const float4* wT4 = reinterpret_cast<const float4*>(wT);
    float acc[4][4];
    #pragma unroll
    for (int i = 0; i < 4; ++i)
        #pragma unroll
        for (int j = 0; j < 4; ++j) acc[i][j] = 0.f;

    #pragma unroll 4
    for (int k4 = 0; k4 < KDIM / 4; ++k4) {
        const float4 w0 = wT4[(size_t)(4 * k4 + 0) * (OUTF / 4) + o4];
        const float4 w1 = wT4[(size_t)(4 * k4 + 1) * (OUTF / 4) + o4];
        const float4 w2 = wT4[(size_t)(4 * k4 + 2) * (OUTF / 4) + o4];
        const float4 w3 = wT4[(size_t)(4 * k4 + 3) * (OUTF / 4) + o4];
        #pragma unroll
        for (int i = 0; i < 4; ++i) {
            const float4 h = *reinterpret_cast<const float4*>(
                &hs[(ng * 4 + i) * HS_STRIDE + 4 * k4]);
            acc[i][0] += h.x*w0.x + h.y*w1.x + h.z*w2.x + h.w*w3.x;
            acc[i][1] += h.x*w0.y + h.y*w1.y + h.z*w2.y + h.w*w3.y;
            acc[i][2] += h.x*w0.z + h.y*w1.z + h.z*w2.z + h.w*w3.z;
            acc[i][3] += h.x*w0.w + h.y*w1.w + h.z*w2.w + h.w*w3.w;
        }
    }

    const float4 bv = *reinterpret_cast<const float4*>(&bias[o4 * 4]);
    #pragma unroll
    for (int i = 0; i < 4; ++i) {
        const int node = base + ng * 4 + i;
        if (node < NNODES) {
            float4 r;
            r.x = acc[i][0] + bv.x; r.y = acc[i][1] + bv.y;
            r.z = acc[i][2] + bv.z; r.w = acc[i][3] + bv.w;
            *reinterpret_cast<float4*>(&out[(size_t)node * OUTF + o4 * 4]) = r;
        }
    }
}

extern "C" void kernel_launch(void* const* d_in, const int* in_sizes, int n_in,
                              void* d_out, int out_size, void* d_ws, size_t ws_size,
                              hipStream_t stream) {
    const float* feat    = reinterpret_cast<const float*>(d_in[0]);
    const int*   off32   = reinterpret_cast<const int*>(d_in[1]);
    const void*  indices = d_in[2];
    const float* weight  = reinterpret_cast<const float*>(d_in[3]);
    const float* bias    = reinterpret_cast<const float*>(d_in[4]);
    float* out = reinterpret_cast<float*>(d_out);

    const size_t featb_bytes = (size_t)NNODES * INF * sizeof(unsigned short); // 12.8 MB
    const size_t wb_bytes    = (size_t)KDIM * OUTF * sizeof(unsigned short);  // 64 KB

    if (ws_size >= featb_bytes + wb_bytes) {
        char* ws = reinterpret_cast<char*>(d_ws);
        unsigned short* featb = reinterpret_cast<unsigned short*>(ws);
        unsigned short* wB    = reinterpret_cast<unsigned short*>(ws + featb_bytes);
        hipLaunchKernelGGL(prep, dim3(CONV_BLOCKS + PACK_BLOCKS), dim3(256), 0, stream,
                           feat, weight, featb, wB);
        hipLaunchKernelGGL(sage_v7, dim3(NBLK), dim3(NTHREADS), 0, stream,
                           featb, off32, indices, wB, bias, out);
    } else if (ws_size >= (size_t)KDIM * OUTF * sizeof(float)) {
        float* wT = reinterpret_cast<float*>(d_ws);
        hipLaunchKernelGGL(transpose_w, dim3((KDIM * OUTF) / 256), dim3(256), 0, stream,
                           weight, wT);
        hipLaunchKernelGGL(sage_fused2, dim3((NNODES + NB - 1) / NB), dim3(NTHREADS), 0, stream,
                           feat, off32, indices, wT, bias, out);
    }
}